// Round 14
// baseline (164.501 us; speedup 1.0000x reference)
//
#include <hip/hip_runtime.h>
#include <hip/hip_bf16.h>

#define NSTEP 50
#define S51 51
#define HID 128
#define MT 64                  // rows per tile
#define BPB 16                 // batch elems per block (block owns them -> no global atomics)
#define RPB (BPB * S51)        // 816 valid rows per block
#define NTILE 13               // ceil(816/64): 832 rows, 16 masked (1.9% waste)
#define GRID (16384 / BPB)     // 1024 blocks
#define BLOCK 256              // 4 waves; wave mi owns hidden slice [mi*32, mi*32+32)

#define SBAR() __builtin_amdgcn_sched_barrier(0)

typedef __attribute__((ext_vector_type(2))) int intx2;
typedef __attribute__((ext_vector_type(8))) int intx8;
typedef __attribute__((ext_vector_type(4))) float floatx4;
typedef __attribute__((ext_vector_type(16))) float floatx16;
typedef __attribute__((ext_vector_type(8))) __bf16 bf16x8;

// 4 x f32 -> 4 packed fp8 e4m3 bytes (v_cvt_pk_fp8_f32, gfx950 OCP e4m3fn)
__device__ __forceinline__ unsigned pk4_fp8(float v0, float v1, float v2, float v3) {
    unsigned r = (unsigned)__builtin_amdgcn_cvt_pk_fp8_f32(v0, v1, 0, false);   // bytes 0,1
    r = (unsigned)__builtin_amdgcn_cvt_pk_fp8_f32(v2, v3, (int)r, true);        // bytes 2,3
    return r;
}

// MX-scaled K=64 fp8 MFMA with unit scales (E8M0 0x7f = 2^0): bit-identical
// fp8*fp8+f32 arithmetic at ~2.1x rate (R23/R25-verified). fmt 0 = e4m3.
__device__ __forceinline__ floatx16 mx_mfma(intx8 a, intx8 b, floatx16 c) {
    return __builtin_amdgcn_mfma_scale_f32_32x32x64_f8f6f4(
        a, b, c, 0, 0, 0, 0x7f7f7f7f, 0, 0x7f7f7f7f);
}

// Swizzled fp8 activation layout: row-major 64x128 bytes, rows = 16 chunks of 8B,
// phys_chunk = chunk ^ (row & 15). XOR-base form (R16-verified). K=64 frag
// (R23-verified): logical chunk c = kq*8 + hi*4 + j -> addr = rbase ^ (kq<<6)
// ^ (j<<3), rbase = l31*128 + ((hi<<5) ^ ((l31&15)<<3))  [+4096 for row l31+32].
// Writes: addr = wbm ^ (g<<3)  [+4096], wbm = (rb+4*hi) ^ (mi<<5).

// Register-only C-operand build (address-taken aggregates spill — R7 lesson)
__device__ __forceinline__ floatx16 ld_bias16(const float* bs, int base) {
    const floatx4 t0 = *(const floatx4*)(&bs[base]);
    const floatx4 t1 = *(const floatx4*)(&bs[base + 8]);
    const floatx4 t2 = *(const floatx4*)(&bs[base + 16]);
    const floatx4 t3 = *(const floatx4*)(&bs[base + 24]);
    floatx16 v = {t0[0], t0[1], t0[2], t0[3], t1[0], t1[1], t1[2], t1[3],
                  t2[0], t2[1], t2[2], t2[3], t3[0], t3[1], t3[2], t3[3]};
    return v;
}

// 32-byte K=64 B-fragment from swizzled LDS: 4 x ds_read_b64 at XOR offsets
__device__ __forceinline__ intx8 ld_frag(const unsigned char* p, int addr) {
    intx2 q0 = *(const intx2*)(p + (addr ^ 0));
    intx2 q1 = *(const intx2*)(p + (addr ^ 8));
    intx2 q2 = *(const intx2*)(p + (addr ^ 16));
    intx2 q3 = *(const intx2*)(p + (addr ^ 24));
    intx8 v;
    v[0] = q0[0]; v[1] = q0[1];
    v[2] = q1[0]; v[3] = q1[1];
    v[4] = q2[0]; v[5] = q2[1];
    v[6] = q3[0]; v[7] = q3[1];
    return v;
}

// fp8 pack of one 32-row D fragment -> swizzled LDS (by-value frag: SSA)
__device__ __forceinline__ void pack4(unsigned char* dst, floatx16 a, int wb) {
#pragma unroll
    for (int g = 0; g < 4; ++g) {
        unsigned p = pk4_fp8(fmaxf(a[4 * g + 0], 0.0f), fmaxf(a[4 * g + 1], 0.0f),
                             fmaxf(a[4 * g + 2], 0.0f), fmaxf(a[4 * g + 3], 0.0f));
        *(unsigned*)(&dst[wb ^ (g << 3)]) = p;
    }
}

// fused L4 dot for one 32-row fragment (this wave's hidden slice)
__device__ __forceinline__ float l4_row(floatx16 c, const float* w4s, int mi, int hi) {
    float p = 0.0f;
#pragma unroll
    for (int g = 0; g < 4; ++g) {
        const floatx4 w4v = *(const floatx4*)(&w4s[mi * 32 + 8 * g + 4 * hi]);
#pragma unroll
        for (int rr = 0; rr < 4; ++rr)
            p = fmaf(fmaxf(c[4 * g + rr], 0.0f), w4v[rr], p);
    }
    return p;
}

// L1 (2->128) on the matrix pipe, serialized row-halves with a sched fence
// between them (R25). Bias b1 in k=2 (R17-verified). ts pads tile 12.
__device__ __forceinline__ void l1_tile(unsigned char* dst, int t,
                                        const float* tsp,
                                        bf16x8 aw, float xv, __bf16 hb, float hm,
                                        int wbm, int l31, int hi, int mi) {
    const int s1 = 4 * t + (l31 >> 4);       // ss for row l31; row l31+32 is +2
    const floatx16 zz = {};
    {
        bf16x8 bx = {};
        bx[0] = (__bf16)(xv * tsp[s1] * hm);  bx[1] = hb;  bx[2] = (__bf16)hm;
        floatx16 d = __builtin_amdgcn_mfma_f32_32x32x16_bf16(aw, bx, zz, 0, 0, 0);
        pack4(dst, d, wbm);
    }
    SBAR();
    {
        bf16x8 bx = {};
        bx[0] = (__bf16)(xv * tsp[s1 + 2] * hm);  bx[1] = hb;  bx[2] = (__bf16)hm;
        floatx16 d = __builtin_amdgcn_mfma_f32_32x32x16_bf16(aw, bx, zz, 0, 0, 0);
        pack4(dst + 4096, d, wbm);
    }
}

// R28 = R26 base (rotation reverted: R27 was -1.3us) + CROSS-FENCE LOAD
// PREFETCH. R27 refuted lockstep-collision; remaining theory: each fenced
// segment exposes a full LDS round-trip (~100+ cyc x 7 segments/phase) that
// 4 waves/SIMD don't hide. New steady schedule per segment: mfma0 -> load
// frag1 (same seg) -> mfma1 -> load NEXT seg's frag0 -> [SBAR] pack ->
// [SBAR] next seg. Load latency hides under pack VALU + MFMA; transients
// grow by exactly one 8-reg frag ({acc 16, frag 8, prefetch 8} = 32 vs 24).
// Peak ~ invariants 96 + 32 = 128 — AT the cap: FETCH/WRITE is the guard.
// LEDGER: R16 runtime-parity fuse (spills), R19 ci-hoist@unfenced (spills),
// R20 MT=128 (occupancy >> barriers), R21 A1-elim (redundant L1 VALU),
// R22 L4-on-MFMA (neutral), R24 source-order serialization (no-op w/o
// fences), R26 ci-hoist@fenced (clean, ~neutral -> not instruction-bound),
// R27 wave rotation (neutral -> not inter-wave collision),
// R9 LDS, R10/R11 occupancy, R13/R14 packed-f32.
// Guards: FETCH <= ~1.5MB, WRITE <= ~1MB (ballooned -> revert to R26);
// absmax exactly 0.03125. Decision rule: clean-but-neutral -> structure
// converged, declare.
template<int PA, bool CONS, bool L2P, bool L3P, bool L1P>
__device__ __forceinline__ void phase(int s,
        unsigned char (&A1)[2][MT * HID], unsigned char (&A2)[2][MT * HID],
        float (&posum)[2][4][MT],
        const floatx16 ci2, const floatx16 ci3, const float* w4s,
        const float* fs, const float* ts,
        float& accq, const intx8 (&w2q)[2], const intx8 (&w3q)[2],
        bf16x8 aw, float xv, __bf16 hb, float hm, float b4v,
        int rbase, int wbm, int tid, int l31, int hi, int mi) {
    constexpr int PB = PA ^ 1;
    // ---- consume tile s-2 partials (posum[PA], written phase s-1); the
    //      phase-top load below may interleave with this (no fence between) ----
    if (CONS) {
        if (tid < MT) {
            int lr = (s - 2) * MT + tid;
            float u = posum[PA][0][tid] + posum[PA][1][tid] + posum[PA][2][tid]
                    + posum[PA][3][tid] + b4v;
            float dz = u > 0.0f ? u + 1.0f : __expf(u);  // elu(u)+1
            accq += dz * fs[lr >> 4];                    // ss = lr>>4
        }
    }
    if (L2P && L3P) {
        // ---- pipelined steady path: prefetch chain L2h0->L2h1->L3h0->L3h1 ----
        intx8 b00 = ld_frag(&A1[PA][0], rbase);              // overlaps consume
        SBAR();
        floatx16 a = mx_mfma(w2q[0], b00, ci2);
        intx8 b01 = ld_frag(&A1[PA][0], rbase ^ 64);
        a = mx_mfma(w2q[1], b01, a);
        intx8 b10 = ld_frag(&A1[PA][0], rbase + 4096);       // prefetch L2h1
        SBAR();
        pack4(&A2[PA][0], a, wbm);
        SBAR();
        a = mx_mfma(w2q[0], b10, ci2);
        intx8 b11 = ld_frag(&A1[PA][0], (rbase ^ 64) + 4096);
        a = mx_mfma(w2q[1], b11, a);
        intx8 g00 = ld_frag(&A2[PB][0], rbase);              // prefetch L3h0
        SBAR();
        pack4(&A2[PA][4096], a, wbm);
        SBAR();
        floatx16 c = mx_mfma(w3q[0], g00, ci3);
        intx8 g01 = ld_frag(&A2[PB][0], rbase ^ 64);
        c = mx_mfma(w3q[1], g01, c);
        intx8 g10 = ld_frag(&A2[PB][0], rbase + 4096);       // prefetch L3h1
        SBAR();
        float p0 = l4_row(c, w4s, mi, hi);
        SBAR();
        c = mx_mfma(w3q[0], g10, ci3);
        intx8 g11 = ld_frag(&A2[PB][0], (rbase ^ 64) + 4096);
        c = mx_mfma(w3q[1], g11, c);
        SBAR();
        float p1 = l4_row(c, w4s, mi, hi);
        p0 += __shfl_xor(p0, 32);
        p1 += __shfl_xor(p1, 32);
        if (hi == 0) {
            posum[PB][mi][l31] = p0;
            posum[PB][mi][l31 + 32] = p1;
        }
    } else {
        // ---- edge phases: R26's fenced serialized path ----
        if (L2P) {
            {
                intx8 b0 = ld_frag(&A1[PA][0], rbase);
                floatx16 a = mx_mfma(w2q[0], b0, ci2);
                intx8 b1 = ld_frag(&A1[PA][0], rbase ^ 64);
                a = mx_mfma(w2q[1], b1, a);
                pack4(&A2[PA][0], a, wbm);
            }
            SBAR();
            {
                intx8 b0 = ld_frag(&A1[PA][0], rbase + 4096);
                floatx16 a = mx_mfma(w2q[0], b0, ci2);
                intx8 b1 = ld_frag(&A1[PA][0], (rbase ^ 64) + 4096);
                a = mx_mfma(w2q[1], b1, a);
                pack4(&A2[PA][4096], a, wbm);
            }
        }
        SBAR();
        if (L3P) {
            float p0, p1;
            {
                intx8 g0 = ld_frag(&A2[PB][0], rbase);
                floatx16 c = mx_mfma(w3q[0], g0, ci3);
                intx8 g1 = ld_frag(&A2[PB][0], rbase ^ 64);
                c = mx_mfma(w3q[1], g1, c);
                p0 = l4_row(c, w4s, mi, hi);
            }
            SBAR();
            {
                intx8 g0 = ld_frag(&A2[PB][0], rbase + 4096);
                floatx16 c = mx_mfma(w3q[0], g0, ci3);
                intx8 g1 = ld_frag(&A2[PB][0], (rbase ^ 64) + 4096);
                c = mx_mfma(w3q[1], g1, c);
                p1 = l4_row(c, w4s, mi, hi);
            }
            p0 += __shfl_xor(p0, 32);
            p1 += __shfl_xor(p1, 32);
            if (hi == 0) {
                posum[PB][mi][l31] = p0;
                posum[PB][mi][l31 + 32] = p1;
            }
        }
    }
    SBAR();
    // ---- L1-MFMA for tile s+1 -> A1[PB] (A1[PB] last read phase s-1) ----
    if (L1P) {
        l1_tile(A1[PB], s + 1, ts, aw, xv, hb, hm, wbm, l31, hi, mi);
    }
    __syncthreads();
}

__launch_bounds__(BLOCK, 4)
__global__ void monotonic_fused(const float* __restrict__ x, const float* __restrict__ h,
                                const float* __restrict__ w1, const float* __restrict__ b1,
                                const float* __restrict__ w2, const float* __restrict__ b2,
                                const float* __restrict__ w3, const float* __restrict__ b3,
                                const float* __restrict__ w4, const float* __restrict__ b4,
                                float* __restrict__ out) {
    __shared__ __align__(16) unsigned char A1[2][MT * HID];  // a1 fp8, 2 x 8 KB
    __shared__ __align__(16) unsigned char A2[2][MT * HID];  // a2 fp8, 2 x 8 KB
    __shared__ float b2s[HID], b3s[HID], w4s[HID];
    __shared__ float fs[S51], ts[56];                        // ts[51..55]=0 pad
    __shared__ float xs[BPB], hs[BPB];
    __shared__ float posum[2][4][MT];                        // parity x mi x row

    const int tid = threadIdx.x;
    const int lane = tid & 63;
    const int mi = tid >> 6;      // wave 0..3 = hidden 32-slice
    const int l31 = lane & 31;
    const int hi = lane >> 5;

    // ---- stage small tensors ----
    if (tid < HID) {
        b2s[tid] = b2[tid]; b3s[tid] = b3[tid]; w4s[tid] = w4[tid];
    }
    if (tid < BPB) {
        xs[tid] = x[blockIdx.x * BPB + tid];
        hs[tid] = h[blockIdx.x * BPB + tid];
    }
    if (tid < 56) {
        if (tid < S51) {
            // Faithful port of compute_cc_weights (verified R1-R27)
            const float PI50 = 0.06283185307179586f;  // pi/50
            float acc = 1.0f;
            for (int i = 2; i <= 50; i += 2) {
                int m = (i * tid) % 100;  // exact argument reduction
                acc += (2.0f / (1.0f - (float)(i * i))) * cosf((float)m * PI50);
            }
            float ccw = acc * 0.04f * ((tid == 0 || tid == NSTEP) ? 0.5f : 1.0f);
            fs[tid] = ccw * 0.5f;                               // folds the (x-x0)*0.5 factor
            ts[tid] = (cosf((float)tid * PI50) + 1.0f) * 0.5f;  // (steps+1)/2
        } else {
            ts[tid] = 0.0f;   // masked rows (ss=51) and dummy tile-13 build (52..55)
        }
    }
    const float b4v = b4[0];
    const float hm = (hi == 0) ? 1.0f : 0.0f;   // zero the k=8..15 half of bf16 frags

    // ---- gather W2^T / W3^T K=64 A-fragments: reg j byte b of block kq holds
    //      W[k = kq*64 + hi*32 + 4j + b][hidden = mi*32 + l31] (coalesced l31) ----
    intx8 w2q[2], w3q[2];
    {
        const int irow = mi * 32 + l31;
#pragma unroll
        for (int kq = 0; kq < 2; ++kq) {
            intx8 t2, t3;
#pragma unroll
            for (int j = 0; j < 8; ++j) {
                const int k0 = kq * 64 + hi * 32 + 4 * j;
                t2[j] = (int)pk4_fp8(w2[(k0 + 0) * HID + irow], w2[(k0 + 1) * HID + irow],
                                     w2[(k0 + 2) * HID + irow], w2[(k0 + 3) * HID + irow]);
                t3[j] = (int)pk4_fp8(w3[(k0 + 0) * HID + irow], w3[(k0 + 1) * HID + irow],
                                     w3[(k0 + 2) * HID + irow], w3[(k0 + 3) * HID + irow]);
            }
            w2q[kq] = t2; w3q[kq] = t3;
        }
    }
    // ---- W1+b1 bf16 A-frag (once): k=0 -> w1[0][j], k=1 -> w1[1][j], k=2 -> b1[j] ----
    bf16x8 aw = {};
    {
        const int j = mi * 32 + l31;
        aw[0] = (__bf16)(w1[j] * hm);
        aw[1] = (__bf16)(w1[HID + j] * hm);
        aw[2] = (__bf16)(b1[j] * hm);
    }
    __syncthreads();

    // ---- loop-invariant bias C-operands, built ONCE (R26 hoist, post-fence) ----
    const floatx16 ci2 = ld_bias16(b2s, mi * 32 + 4 * hi);
    const floatx16 ci3 = ld_bias16(b3s, mi * 32 + 4 * hi);

    // per-lane constants: row remap lr = ss*16 + bbl  =>  bbl = r&15 fixed per lane
    const float xv = xs[l31 & 15];
    const __bf16 hb = (__bf16)(hs[l31 & 15] * hm);
    float accq = 0.0f;            // wave-0 per-lane quadrature accumulator (bbl = tid&15)

    // XOR-addressing bases (R16/R23-verified)
    const int rb    = l31 * HID + ((l31 & 15) << 3);
    const int rbase = l31 * HID + ((hi << 5) ^ ((l31 & 15) << 3));
    const int wbm   = (rb + 4 * hi) ^ (mi << 5);

    // ---- L1 for tile 0 -> A1[0] ----
    l1_tile(A1[0], 0, ts, aw, xv, hb, hm, wbm, l31, hi, mi);
    __syncthreads();

#define PHASE_ARGS A1, A2, posum, ci2, ci3, w4s, fs, ts, accq, w2q, w3q, \
                   aw, xv, hb, hm, b4v, rbase, wbm, tid, l31, hi, mi
    // edge phases 0,1; steady fused 2..12; edge 13 (parity literal throughout)
    phase<0, false, true, false, true >(0, PHASE_ARGS);
    phase<1, false, true, true,  true >(1, PHASE_ARGS);
    for (int it = 0; it < 5; ++it) {
        phase<0, true, true, true, true>(2 + 2 * it, PHASE_ARGS);
        phase<1, true, true, true, true>(3 + 2 * it, PHASE_ARGS);
    }
    phase<0, true, true,  true, true >(12, PHASE_ARGS);
    phase<1, true, false, true, false>(13, PHASE_ARGS);
#undef PHASE_ARGS

    // final consume: tile 12 (posum[0], written by L4@13), masked rows 816..831;
    // then cross-lane reduce (lanes l, l^16, l^32, l^48 share bbl = l&15).
    if (tid < MT) {
        int lr = (NTILE - 1) * MT + tid;
        if (lr < RPB) {
            float u = posum[0][0][tid] + posum[0][1][tid] + posum[0][2][tid]
                    + posum[0][3][tid] + b4v;
            float dz = u > 0.0f ? u + 1.0f : __expf(u);
            accq += dz * fs[lr >> 4];
        }
        accq += __shfl_xor(accq, 16);
        accq += __shfl_xor(accq, 32);
        if (tid < BPB) out[blockIdx.x * BPB + tid] = hs[tid] + accq * xs[tid];
    }
}

extern "C" void kernel_launch(void* const* d_in, const int* in_sizes, int n_in,
                              void* d_out, int out_size, void* d_ws, size_t ws_size,
                              hipStream_t stream) {
    const float* x  = (const float*)d_in[0];
    const float* h  = (const float*)d_in[1];
    const float* w1 = (const float*)d_in[2];
    const float* b1 = (const float*)d_in[3];
    const float* w2 = (const float*)d_in[4];
    const float* b2 = (const float*)d_in[5];
    const float* w3 = (const float*)d_in[6];
    const float* b3 = (const float*)d_in[7];
    const float* w4 = (const float*)d_in[8];
    const float* b4 = (const float*)d_in[9];
    float* out = (float*)d_out;

    monotonic_fused<<<GRID, BLOCK, 0, stream>>>(x, h, w1, b1, w2, b2, w3, b3, w4, b4, out);
}

// Round 15
// 116.173 us; speedup vs baseline: 1.4160x; 1.4160x over previous
//
#include <hip/hip_runtime.h>
#include <hip/hip_bf16.h>

#define NSTEP 50
#define S51 51
#define HID 128
#define MT 64                  // rows per tile
#define BPB 16                 // batch elems per block (block owns them -> no global atomics)
#define RPB (BPB * S51)        // 816 valid rows per block
#define NTILE 13               // ceil(816/64): 832 rows, 16 masked (1.9% waste)
#define GRID (16384 / BPB)     // 1024 blocks
#define BLOCK 256              // 4 waves; wave mi owns hidden slice [mi*32, mi*32+32)

#define SBAR() __builtin_amdgcn_sched_barrier(0)
#define PRIO(n) __builtin_amdgcn_s_setprio(n)

typedef __attribute__((ext_vector_type(2))) int intx2;
typedef __attribute__((ext_vector_type(8))) int intx8;
typedef __attribute__((ext_vector_type(4))) float floatx4;
typedef __attribute__((ext_vector_type(16))) float floatx16;
typedef __attribute__((ext_vector_type(8))) __bf16 bf16x8;

// 4 x f32 -> 4 packed fp8 e4m3 bytes (v_cvt_pk_fp8_f32, gfx950 OCP e4m3fn)
__device__ __forceinline__ unsigned pk4_fp8(float v0, float v1, float v2, float v3) {
    unsigned r = (unsigned)__builtin_amdgcn_cvt_pk_fp8_f32(v0, v1, 0, false);   // bytes 0,1
    r = (unsigned)__builtin_amdgcn_cvt_pk_fp8_f32(v2, v3, (int)r, true);        // bytes 2,3
    return r;
}

// MX-scaled K=64 fp8 MFMA with unit scales (E8M0 0x7f = 2^0): bit-identical
// fp8*fp8+f32 arithmetic at ~2.1x rate (R23/R25-verified). fmt 0 = e4m3.
__device__ __forceinline__ floatx16 mx_mfma(intx8 a, intx8 b, floatx16 c) {
    return __builtin_amdgcn_mfma_scale_f32_32x32x64_f8f6f4(
        a, b, c, 0, 0, 0, 0x7f7f7f7f, 0, 0x7f7f7f7f);
}

// Swizzled fp8 activation layout: row-major 64x128 bytes, rows = 16 chunks of 8B,
// phys_chunk = chunk ^ (row & 15). XOR-base form (R16-verified). K=64 frag
// (R23-verified): logical chunk c = kq*8 + hi*4 + j -> addr = rbase ^ (kq<<6)
// ^ (j<<3), rbase = l31*128 + ((hi<<5) ^ ((l31&15)<<3))  [+4096 for row l31+32].
// Writes: addr = wbm ^ (g<<3)  [+4096], wbm = (rb+4*hi) ^ (mi<<5).

// Register-only C-operand build (address-taken aggregates spill — R7 lesson)
__device__ __forceinline__ floatx16 ld_bias16(const float* bs, int base) {
    const floatx4 t0 = *(const floatx4*)(&bs[base]);
    const floatx4 t1 = *(const floatx4*)(&bs[base + 8]);
    const floatx4 t2 = *(const floatx4*)(&bs[base + 16]);
    const floatx4 t3 = *(const floatx4*)(&bs[base + 24]);
    floatx16 v = {t0[0], t0[1], t0[2], t0[3], t1[0], t1[1], t1[2], t1[3],
                  t2[0], t2[1], t2[2], t2[3], t3[0], t3[1], t3[2], t3[3]};
    return v;
}

// 32-byte K=64 B-fragment from swizzled LDS: 4 x ds_read_b64 at XOR offsets
__device__ __forceinline__ intx8 ld_frag(const unsigned char* p, int addr) {
    intx2 q0 = *(const intx2*)(p + (addr ^ 0));
    intx2 q1 = *(const intx2*)(p + (addr ^ 8));
    intx2 q2 = *(const intx2*)(p + (addr ^ 16));
    intx2 q3 = *(const intx2*)(p + (addr ^ 24));
    intx8 v;
    v[0] = q0[0]; v[1] = q0[1];
    v[2] = q1[0]; v[3] = q1[1];
    v[4] = q2[0]; v[5] = q2[1];
    v[6] = q3[0]; v[7] = q3[1];
    return v;
}

// fp8 pack of one 32-row D fragment -> swizzled LDS (by-value frag: SSA)
__device__ __forceinline__ void pack4(unsigned char* dst, floatx16 a, int wb) {
#pragma unroll
    for (int g = 0; g < 4; ++g) {
        unsigned p = pk4_fp8(fmaxf(a[4 * g + 0], 0.0f), fmaxf(a[4 * g + 1], 0.0f),
                             fmaxf(a[4 * g + 2], 0.0f), fmaxf(a[4 * g + 3], 0.0f));
        *(unsigned*)(&dst[wb ^ (g << 3)]) = p;
    }
}

// fused L4 dot for one 32-row fragment (this wave's hidden slice)
__device__ __forceinline__ float l4_row(floatx16 c, const float* w4s, int mi, int hi) {
    float p = 0.0f;
#pragma unroll
    for (int g = 0; g < 4; ++g) {
        const floatx4 w4v = *(const floatx4*)(&w4s[mi * 32 + 8 * g + 4 * hi]);
#pragma unroll
        for (int rr = 0; rr < 4; ++rr)
            p = fmaf(fmaxf(c[4 * g + rr], 0.0f), w4v[rr], p);
    }
    return p;
}

// L1 (2->128) on the matrix pipe, serialized row-halves with a sched fence
// between them (R25). Bias b1 in k=2 (R17-verified). ts pads tile 12.
__device__ __forceinline__ void l1_tile(unsigned char* dst, int t,
                                        const float* tsp,
                                        bf16x8 aw, float xv, __bf16 hb, float hm,
                                        int wbm, int l31, int hi, int mi) {
    const int s1 = 4 * t + (l31 >> 4);       // ss for row l31; row l31+32 is +2
    const floatx16 zz = {};
    {
        bf16x8 bx = {};
        bx[0] = (__bf16)(xv * tsp[s1] * hm);  bx[1] = hb;  bx[2] = (__bf16)hm;
        PRIO(1);
        floatx16 d = __builtin_amdgcn_mfma_f32_32x32x16_bf16(aw, bx, zz, 0, 0, 0);
        PRIO(0);
        pack4(dst, d, wbm);
    }
    SBAR();
    {
        bf16x8 bx = {};
        bx[0] = (__bf16)(xv * tsp[s1 + 2] * hm);  bx[1] = hb;  bx[2] = (__bf16)hm;
        PRIO(1);
        floatx16 d = __builtin_amdgcn_mfma_f32_32x32x16_bf16(aw, bx, zz, 0, 0, 0);
        PRIO(0);
        pack4(dst + 4096, d, wbm);
    }
}

// R29 = R26 EXACT REVERT (proven best: 55.4us steady / 116.8 harness) +
// s_setprio(1) around MFMA clusters (T5 — zero reg/instr cost; fences give
// waves role diversity via barrier-arrival jitter, the regime where setprio
// paid +4-7% elsewhere). R28 post-mortem: +8-reg prefetch hit the exact
// 128-reg cap -> catastrophic spills (FETCH 200MB, 103us). All three stall
// theories now dispositioned: instruction count (R26 <1%), inter-wave
// collision (R27 -1.3us), intra-wave latency (R28 unfundable in registers).
// Busy = VALU 57% + MFMA 21% ~= 78% combined issue; the residual is a
// latency/issue-mix bound whose escape routes (more regs, fewer barriers,
// lower occupancy) are all hardware-budget-closed.
// LEDGER: R16 runtime-parity fuse (spills), R19 ci-hoist@unfenced (spills),
// R20 MT=128 (occupancy >> barriers), R21 A1-elim (redundant L1 VALU),
// R22 L4-on-MFMA (neutral), R24 source-order serialization (no-op w/o
// fences), R26 ci-hoist@fenced (kept; ~neutral), R27 wave rotation
// (negative), R28 cross-fence prefetch (spills @128-reg cap),
// R9 LDS, R10/R11 occupancy, R13/R14 packed-f32.
// Guards: FETCH <= ~1.5MB, WRITE <= ~1MB; absmax exactly 0.03125.
// Decision rule: neutral -> structure converged; declare next round.
template<int PA, bool CONS, bool L2P, bool L3P, bool L1P>
__device__ __forceinline__ void phase(int s,
        unsigned char (&A1)[2][MT * HID], unsigned char (&A2)[2][MT * HID],
        float (&posum)[2][4][MT],
        const floatx16 ci2, const floatx16 ci3, const float* w4s,
        const float* fs, const float* ts,
        float& accq, const intx8 (&w2q)[2], const intx8 (&w3q)[2],
        bf16x8 aw, float xv, __bf16 hb, float hm, float b4v,
        int rbase, int wbm, int tid, int l31, int hi, int mi) {
    constexpr int PB = PA ^ 1;
    // ---- consume tile s-2 partials (posum[PA], written phase s-1) ----
    if (CONS) {
        if (tid < MT) {
            int lr = (s - 2) * MT + tid;
            float u = posum[PA][0][tid] + posum[PA][1][tid] + posum[PA][2][tid]
                    + posum[PA][3][tid] + b4v;
            float dz = u > 0.0f ? u + 1.0f : __expf(u);  // elu(u)+1
            accq += dz * fs[lr >> 4];                    // ss = lr>>4
        }
    }
    SBAR();
    // ---- L2 on tile s (read A1[PA]), fenced serialized halves -> A2[PA] ----
    if (L2P) {
        {
            intx8 b0 = ld_frag(&A1[PA][0], rbase);
            PRIO(1);
            floatx16 a = mx_mfma(w2q[0], b0, ci2);
            intx8 b1 = ld_frag(&A1[PA][0], rbase ^ 64);
            a = mx_mfma(w2q[1], b1, a);
            PRIO(0);
            pack4(&A2[PA][0], a, wbm);
        }
        SBAR();
        {
            intx8 b0 = ld_frag(&A1[PA][0], rbase + 4096);
            PRIO(1);
            floatx16 a = mx_mfma(w2q[0], b0, ci2);
            intx8 b1 = ld_frag(&A1[PA][0], (rbase ^ 64) + 4096);
            a = mx_mfma(w2q[1], b1, a);
            PRIO(0);
            pack4(&A2[PA][4096], a, wbm);
        }
    }
    SBAR();
    // ---- L3 on tile s-1 (read A2[PB]), fenced halves + fused L4 -> posum[PB] ----
    if (L3P) {
        float p0, p1;
        {
            intx8 g0 = ld_frag(&A2[PB][0], rbase);
            PRIO(1);
            floatx16 c = mx_mfma(w3q[0], g0, ci3);
            intx8 g1 = ld_frag(&A2[PB][0], rbase ^ 64);
            c = mx_mfma(w3q[1], g1, c);
            PRIO(0);
            p0 = l4_row(c, w4s, mi, hi);
        }
        SBAR();
        {
            intx8 g0 = ld_frag(&A2[PB][0], rbase + 4096);
            PRIO(1);
            floatx16 c = mx_mfma(w3q[0], g0, ci3);
            intx8 g1 = ld_frag(&A2[PB][0], (rbase ^ 64) + 4096);
            c = mx_mfma(w3q[1], g1, c);
            PRIO(0);
            p1 = l4_row(c, w4s, mi, hi);
        }
        p0 += __shfl_xor(p0, 32);
        p1 += __shfl_xor(p1, 32);
        if (hi == 0) {
            posum[PB][mi][l31] = p0;
            posum[PB][mi][l31 + 32] = p1;
        }
    }
    SBAR();
    // ---- L1-MFMA for tile s+1 -> A1[PB] (A1[PB] last read phase s-1) ----
    if (L1P) {
        l1_tile(A1[PB], s + 1, ts, aw, xv, hb, hm, wbm, l31, hi, mi);
    }
    __syncthreads();
}

__launch_bounds__(BLOCK, 4)
__global__ void monotonic_fused(const float* __restrict__ x, const float* __restrict__ h,
                                const float* __restrict__ w1, const float* __restrict__ b1,
                                const float* __restrict__ w2, const float* __restrict__ b2,
                                const float* __restrict__ w3, const float* __restrict__ b3,
                                const float* __restrict__ w4, const float* __restrict__ b4,
                                float* __restrict__ out) {
    __shared__ __align__(16) unsigned char A1[2][MT * HID];  // a1 fp8, 2 x 8 KB
    __shared__ __align__(16) unsigned char A2[2][MT * HID];  // a2 fp8, 2 x 8 KB
    __shared__ float b2s[HID], b3s[HID], w4s[HID];
    __shared__ float fs[S51], ts[56];                        // ts[51..55]=0 pad
    __shared__ float xs[BPB], hs[BPB];
    __shared__ float posum[2][4][MT];                        // parity x mi x row

    const int tid = threadIdx.x;
    const int lane = tid & 63;
    const int mi = tid >> 6;      // wave 0..3 = hidden 32-slice
    const int l31 = lane & 31;
    const int hi = lane >> 5;

    // ---- stage small tensors ----
    if (tid < HID) {
        b2s[tid] = b2[tid]; b3s[tid] = b3[tid]; w4s[tid] = w4[tid];
    }
    if (tid < BPB) {
        xs[tid] = x[blockIdx.x * BPB + tid];
        hs[tid] = h[blockIdx.x * BPB + tid];
    }
    if (tid < 56) {
        if (tid < S51) {
            // Faithful port of compute_cc_weights (verified R1-R28)
            const float PI50 = 0.06283185307179586f;  // pi/50
            float acc = 1.0f;
            for (int i = 2; i <= 50; i += 2) {
                int m = (i * tid) % 100;  // exact argument reduction
                acc += (2.0f / (1.0f - (float)(i * i))) * cosf((float)m * PI50);
            }
            float ccw = acc * 0.04f * ((tid == 0 || tid == NSTEP) ? 0.5f : 1.0f);
            fs[tid] = ccw * 0.5f;                               // folds the (x-x0)*0.5 factor
            ts[tid] = (cosf((float)tid * PI50) + 1.0f) * 0.5f;  // (steps+1)/2
        } else {
            ts[tid] = 0.0f;   // masked rows (ss=51) and dummy tile-13 build (52..55)
        }
    }
    const float b4v = b4[0];
    const float hm = (hi == 0) ? 1.0f : 0.0f;   // zero the k=8..15 half of bf16 frags

    // ---- gather W2^T / W3^T K=64 A-fragments: reg j byte b of block kq holds
    //      W[k = kq*64 + hi*32 + 4j + b][hidden = mi*32 + l31] (coalesced l31) ----
    intx8 w2q[2], w3q[2];
    {
        const int irow = mi * 32 + l31;
#pragma unroll
        for (int kq = 0; kq < 2; ++kq) {
            intx8 t2, t3;
#pragma unroll
            for (int j = 0; j < 8; ++j) {
                const int k0 = kq * 64 + hi * 32 + 4 * j;
                t2[j] = (int)pk4_fp8(w2[(k0 + 0) * HID + irow], w2[(k0 + 1) * HID + irow],
                                     w2[(k0 + 2) * HID + irow], w2[(k0 + 3) * HID + irow]);
                t3[j] = (int)pk4_fp8(w3[(k0 + 0) * HID + irow], w3[(k0 + 1) * HID + irow],
                                     w3[(k0 + 2) * HID + irow], w3[(k0 + 3) * HID + irow]);
            }
            w2q[kq] = t2; w3q[kq] = t3;
        }
    }
    // ---- W1+b1 bf16 A-frag (once): k=0 -> w1[0][j], k=1 -> w1[1][j], k=2 -> b1[j] ----
    bf16x8 aw = {};
    {
        const int j = mi * 32 + l31;
        aw[0] = (__bf16)(w1[j] * hm);
        aw[1] = (__bf16)(w1[HID + j] * hm);
        aw[2] = (__bf16)(b1[j] * hm);
    }
    __syncthreads();

    // ---- loop-invariant bias C-operands, built ONCE (R26 hoist, post-fence) ----
    const floatx16 ci2 = ld_bias16(b2s, mi * 32 + 4 * hi);
    const floatx16 ci3 = ld_bias16(b3s, mi * 32 + 4 * hi);

    // per-lane constants: row remap lr = ss*16 + bbl  =>  bbl = r&15 fixed per lane
    const float xv = xs[l31 & 15];
    const __bf16 hb = (__bf16)(hs[l31 & 15] * hm);
    float accq = 0.0f;            // wave-0 per-lane quadrature accumulator (bbl = tid&15)

    // XOR-addressing bases (R16/R23-verified)
    const int rb    = l31 * HID + ((l31 & 15) << 3);
    const int rbase = l31 * HID + ((hi << 5) ^ ((l31 & 15) << 3));
    const int wbm   = (rb + 4 * hi) ^ (mi << 5);

    // ---- L1 for tile 0 -> A1[0] ----
    l1_tile(A1[0], 0, ts, aw, xv, hb, hm, wbm, l31, hi, mi);
    __syncthreads();

#define PHASE_ARGS A1, A2, posum, ci2, ci3, w4s, fs, ts, accq, w2q, w3q, \
                   aw, xv, hb, hm, b4v, rbase, wbm, tid, l31, hi, mi
    // edge phases 0,1; steady fused 2..12; edge 13 (parity literal throughout)
    phase<0, false, true, false, true >(0, PHASE_ARGS);
    phase<1, false, true, true,  true >(1, PHASE_ARGS);
    for (int it = 0; it < 5; ++it) {
        phase<0, true, true, true, true>(2 + 2 * it, PHASE_ARGS);
        phase<1, true, true, true, true>(3 + 2 * it, PHASE_ARGS);
    }
    phase<0, true, true,  true, true >(12, PHASE_ARGS);
    phase<1, true, false, true, false>(13, PHASE_ARGS);
#undef PHASE_ARGS

    // final consume: tile 12 (posum[0], written by L4@13), masked rows 816..831;
    // then cross-lane reduce (lanes l, l^16, l^32, l^48 share bbl = l&15).
    if (tid < MT) {
        int lr = (NTILE - 1) * MT + tid;
        if (lr < RPB) {
            float u = posum[0][0][tid] + posum[0][1][tid] + posum[0][2][tid]
                    + posum[0][3][tid] + b4v;
            float dz = u > 0.0f ? u + 1.0f : __expf(u);
            accq += dz * fs[lr >> 4];
        }
        accq += __shfl_xor(accq, 16);
        accq += __shfl_xor(accq, 32);
        if (tid < BPB) out[blockIdx.x * BPB + tid] = hs[tid] + accq * xs[tid];
    }
}

extern "C" void kernel_launch(void* const* d_in, const int* in_sizes, int n_in,
                              void* d_out, int out_size, void* d_ws, size_t ws_size,
                              hipStream_t stream) {
    const float* x  = (const float*)d_in[0];
    const float* h  = (const float*)d_in[1];
    const float* w1 = (const float*)d_in[2];
    const float* b1 = (const float*)d_in[3];
    const float* w2 = (const float*)d_in[4];
    const float* b2 = (const float*)d_in[5];
    const float* w3 = (const float*)d_in[6];
    const float* b3 = (const float*)d_in[7];
    const float* w4 = (const float*)d_in[8];
    const float* b4 = (const float*)d_in[9];
    float* out = (float*)d_out;

    monotonic_fused<<<GRID, BLOCK, 0, stream>>>(x, h, w1, b1, w2, b2, w3, b3, w4, b4, out);
}